// Round 14
// baseline (158.025 us; speedup 1.0000x reference)
//
#include <hip/hip_runtime.h>
#include <stdint.h>

#define B_SZ 4096
#define D_SZ 512
#define SHIFT 64.0f

typedef __attribute__((ext_vector_type(4))) float floatx4;
typedef __attribute__((ext_vector_type(2))) long lng2;
typedef unsigned char u8;
typedef unsigned int u32;

#define GLD_LDS16(gp, sp)                                                              \
    __builtin_amdgcn_global_load_lds(                                                  \
        (const __attribute__((address_space(1))) void*)(gp),                           \
        (__attribute__((address_space(3))) void*)(sp), 16, 0, 0)

#define FP8MFMA(accv, av, bv)                                                          \
    accv = __builtin_amdgcn_mfma_f32_16x16x32_fp8_fp8(av, bv, accv, 0, 0, 0)

// ---- K1: fp32->fp8(e4m3) convert (K-interleaved layout) + per-row time,
//      fused: histogram (block 0), accumulator zeroing, entailment partials.
//      K-perm: within each 64B K-window, 8B group (h,c) -> slot c*2+h; applied
//      to BOTH operands => Grammian unchanged. ----
__global__ __launch_bounds__(256) void prep_kernel(
    const float* __restrict__ img, const float* __restrict__ dna,
    const float* __restrict__ txt, const float* __restrict__ curv_p,
    const int* __restrict__ labels, int* __restrict__ hist,
    u8* __restrict__ f8, float* __restrict__ times,
    float* __restrict__ zero_f, float* __restrict__ ent_partial) {
    __shared__ int lhist[512];
    __shared__ float red[4];
    int t = threadIdx.x;
    int gid = blockIdx.x * 256 + t;
    if (gid < 49155) zero_f[gid] = 0.0f;    // rsum/csum + ce_acc/ent_acc/done

    if (blockIdx.x == 0) {                  // label histogram, single block
        lhist[t] = 0; lhist[t + 256] = 0;
        __syncthreads();
        for (int n = t; n < B_SZ; n += 256) atomicAdd(&lhist[labels[n]], 1);
        __syncthreads();
        hist[t] = lhist[t]; hist[t + 256] = lhist[t + 256];
    }

    int wave = gid >> 6;  // 0..12287
    int lane = t & 63;
    const float* src = (wave < B_SZ) ? img : (wave < 2 * B_SZ) ? dna : txt;
    int row = wave & (B_SZ - 1);
    const float* p = src + row * D_SZ + lane * 8;
    float4 v0 = *(const float4*)(p);
    float4 v1 = *(const float4*)(p + 4);
    float ss = v0.x*v0.x + v0.y*v0.y + v0.z*v0.z + v0.w*v0.w
             + v1.x*v1.x + v1.y*v1.y + v1.z*v1.z + v1.w*v1.w;
    u32 w0 = __builtin_amdgcn_cvt_pk_fp8_f32(v0.x, v0.y, 0, false);
    w0 = __builtin_amdgcn_cvt_pk_fp8_f32(v0.z, v0.w, w0, true);
    u32 w1 = __builtin_amdgcn_cvt_pk_fp8_f32(v1.x, v1.y, 0, false);
    w1 = __builtin_amdgcn_cvt_pk_fp8_f32(v1.z, v1.w, w1, true);
    uint2 pk; pk.x = w0; pk.y = w1;
    // lane = 8B group: window lane>>3, half (lane>>2)&1, chunk lane&3
    int gperm = (lane & 56) | ((lane & 3) << 1) | ((lane >> 2) & 1);
    *(uint2*)(f8 + (size_t)wave * D_SZ + gperm * 8) = pk;

    bool isdna = (wave >= B_SZ) && (wave < 2 * B_SZ);
    float dot = 0.0f, ssy = 0.0f;
    if (isdna) {                            // matching image row for entailment
        const float* y = img + row * D_SZ + lane * 8;
        float4 y0 = *(const float4*)y, y1 = *(const float4*)(y + 4);
        dot = v0.x*y0.x + v0.y*y0.y + v0.z*y0.z + v0.w*y0.w
            + v1.x*y1.x + v1.y*y1.y + v1.z*y1.z + v1.w*y1.w;
        ssy = y0.x*y0.x + y0.y*y0.y + y0.z*y0.z + y0.w*y0.w
            + y1.x*y1.x + y1.y*y1.y + y1.z*y1.z + y1.w*y1.w;
    }
    #pragma unroll
    for (int m = 1; m < 64; m <<= 1) {
        ss += __shfl_xor(ss, m);
        if (isdna) { dot += __shfl_xor(dot, m); ssy += __shfl_xor(ssy, m); }
    }
    float curv = curv_p[0];
    float ep = 0.0f;
    if (lane == 0) {
        float xt = sqrtf(1.0f / curv + ss);
        times[wave] = xt;
        if (isdna) {
            float yt = sqrtf(1.0f / curv + ssy);
            float nx = sqrtf(ss);
            float c = curv * (dot - xt * yt);                      // <= -1
            float numer = yt + c * xt;
            float denom = nx * sqrtf(fmaxf(c * c - 1.0f, 0.0f));
            float ai = numer / (denom + 1e-8f);
            ai = fminf(fmaxf(ai, -1.0f + 1e-8f), 1.0f - 1e-8f);
            float ang = acosf(ai);
            float as_in = 0.2f / (nx * sqrtf(curv) + 1e-6f);       // 2*min_radius
            as_in = fminf(fmaxf(as_in, -1.0f + 1e-6f), 1.0f - 1e-6f);
            float ap = asinf(as_in);
            ep = fmaxf(ang - ap, 0.0f);
        }
    }
    if (blockIdx.x >= 1024 && blockIdx.x < 2048) {   // pure-dna blocks
        if (lane == 0) red[t >> 6] = ep;
        __syncthreads();
        if (t == 0) ent_partial[blockIdx.x - 1024] = red[0] + red[1] + red[2] + red[3];
    }
}

// ---- K2: batched fp8 MFMA GEMM (A·B^T), 128x128 tile, 8 waves, 32x64/wave.
//      R31 = R30 persistent 6-tile kernel (champion: gemm 77us, total 150)
//      + FUSED FINALIZE (removes the 3rd kernel launch + its gap).
//      Mechanism: after its 6 tiles each block orders its epilogue atomics
//      with s_waitcnt vmcnt(0), then atomicAdd(done,1). The 512th arrival
//      runs finalize with its 512 threads (8 n each).
//      Coherence audit (G16): rsum/csum were written ONLY via device-scope
//      atomicAdd -> finalize reads them with atomicAdd(p,0.0f) (coherent-
//      read idiom, same as old finalize_kernel). hist/ent_partial/labels/
//      times were written by the PREP kernel -> kernel-boundary flush makes
//      plain loads safe. No __threadfence (R15 storm), no spin (no deadlock:
//      last-to-arrive finalizes, everyone else exits).
//      In-tile schedule unchanged (R24/R30): counted-vmcnt dist-2, vmcnt(2)
//      [2 GLD/stage -> in-flight 4 at K-step top], 1 barrier/K-step, no
//      setprio; cross-tile stage(0) at si==7, stage(1) post-loop.
//      Ledger: R30 persistent = 77us gemm / 150 total (champion). R29
//      vmcnt(4) ledger bug -> race (ledgers are per-geometry, re-derive!).
//      R28/R19 256^2 spill (dead family). R27 256thr VGPR pin. R26 reg-dbuf
//      spill. R25 dist-3+setprio regressed. R24 = 88.5. R23 XCD remap
//      regressed. R22 direct-L2 regressed. R20 4-phase +10%. R15 per-block
//      threadfence storm. Non-gemm was ~73us const across R17-R30.
__global__ __launch_bounds__(512, 4) void gemm_epi_kernel(
    const u8* __restrict__ f8, const float* __restrict__ times,
    const int* __restrict__ labels,
    const float* __restrict__ ls_p, const float* __restrict__ curv_p,
    float* __restrict__ rsum_e, float* __restrict__ rsum_t,
    float* __restrict__ csum_e, float* __restrict__ csum_t,
    const int* __restrict__ hist, const float* __restrict__ ent_partial,
    int* __restrict__ done, float* __restrict__ out) {
    __shared__ u8 sA[3][128 * 64];    // 24 KB
    __shared__ u8 sB[3][128 * 64];    // 24 KB -> 48 KB total, 2 blocks/CU
    __shared__ float fin_red[8], fin_red2[8];
    __shared__ int last_flag;

    int t = threadIdx.x;
    int wave = t >> 6, lane = t & 63;
    int wr = wave >> 1;                   // row 32-group (0..3)
    int wc = wave & 1;                    // col 64-group (0..1)
    int chunk = (t & 3) ^ ((t >> 3) & 3);
    int q = lane >> 4, s = lane & 15;
    int slot16 = (q ^ ((s >> 1) & 3)) << 4;
    int aBase = (wr * 32 + s) * 64 + slot16;     // + ii*1024 per fragment
    int bBase = (wc * 64 + s) * 64 + slot16;     // + j*1024 per fragment

    float ls = ls_p[0];
    float curv = curv_p[0];
    float rsc = rsqrtf(curv);
    float c2 = -ls * rsc;
    float c1 = c2 * 0.69314718f;
    float sh2p = SHIFT * 1.44269504f + c2;

    const u8* gA = nullptr;  const u8* gB = nullptr;

    #pragma unroll 1
    for (int tile = 0; tile < 6; ++tile) {
        int tl  = blockIdx.x * 6 + tile;          // 0..3071
        int z   = tl >> 10;                       // 0:(img,dna) 1:(img,txt) 2:(dna,txt)
        int rem = tl & 1023;
        int rowBlk = (rem >> 5) * 128;
        int colBlk = (rem & 31) * 128;
        int pa = (z == 2) ? 1 : 0;
        int pb = (z == 0) ? 1 : 2;
        const u8* A  = f8 + (size_t)pa * (B_SZ * D_SZ);
        const u8* Bm = f8 + (size_t)pb * (B_SZ * D_SZ);
        // Staging ptrs (R21/R24-verified mapping): thread t -> row t>>2,
        // global chunk (t&3)^((t>>3)&3); LDS linear => involution swizzle.
        const u8* gA_n = A  + (size_t)(rowBlk + (t >> 2)) * D_SZ + chunk * 16;
        const u8* gB_n = Bm + (size_t)(colBlk + (t >> 2)) * D_SZ + chunk * 16;

        if (tile == 0) {
            // cold prologue: stage K-steps 0,1 into buffers 0,1
            GLD_LDS16(gA_n,      &sA[0][wave * 1024]);
            GLD_LDS16(gB_n,      &sB[0][wave * 1024]);
            GLD_LDS16(gA_n + 64, &sA[1][wave * 1024]);
            GLD_LDS16(gB_n + 64, &sB[1][wave * 1024]);
        }
        // (for tile>0, stage(0)/stage(1) were issued during the previous
        //  tile's si==7 body and pre-epilogue, using gAx/gBx)
        gA = gA_n; gB = gB_n;

        floatx4 acc[2][4];
        #pragma unroll
        for (int ii = 0; ii < 2; ++ii)
            #pragma unroll
            for (int j = 0; j < 4; ++j) acc[ii][j] = (floatx4){0.f, 0.f, 0.f, 0.f};

        // next-tile staging ptrs (used only when tile<5)
        int tln  = tl + 1;
        int zn   = tln >> 10;
        int remn = tln & 1023;
        const u8* An  = f8 + (size_t)((zn == 2) ? 1 : 0) * (B_SZ * D_SZ);
        const u8* Bn  = f8 + (size_t)((zn == 0) ? 1 : 2) * (B_SZ * D_SZ);
        const u8* gAx = An + (size_t)(((remn >> 5) * 128) + (t >> 2)) * D_SZ + chunk * 16;
        const u8* gBx = Bn + (size_t)(((remn & 31) * 128) + (t >> 2)) * D_SZ + chunk * 16;

        #pragma unroll
        for (int si = 0; si < D_SZ / 64; ++si) {
            const int cur = si % 3;
            // own prior-step ds_reads consumed before the barrier (buffer-
            // reuse safety for the distance-2 DMA target); then wait ONLY
            // stage(si): in-flight = stage(si)+stage(si+1) = 4 -> vmcnt(2).
            asm volatile("s_waitcnt lgkmcnt(0)" ::: "memory");
            if (si < 7) { asm volatile("s_waitcnt vmcnt(2)" ::: "memory"); }
            else        { asm volatile("s_waitcnt vmcnt(0)" ::: "memory"); }
            asm volatile("s_barrier" ::: "memory");
            if (si < 6) {
                // prefetch distance 2: stage(si+2) into buf[(si+2)%3]
                // (= buf[(si-1)%3], fully read before barrier(si)).
                const int nxb = (si + 2) % 3;
                const int ko  = (si + 2) * 64;
                GLD_LDS16(gA + ko, &sA[nxb][wave * 1024]);
                GLD_LDS16(gB + ko, &sB[nxb][wave * 1024]);
            } else if (si == 7 && tile < 5) {
                // cross-tile: next tile's stage(0) into buf0 (last read at
                // si==6; all waves past barrier(7) -> safe).
                GLD_LDS16(gAx, &sA[0][wave * 1024]);
                GLD_LDS16(gBx, &sB[0][wave * 1024]);
            }
            const u8* pA = &sA[cur][0];
            const u8* pB = &sB[cur][0];
            lng2 a0 = *(const lng2*)(pA + aBase);
            lng2 a1 = *(const lng2*)(pA + aBase + 1024);
            lng2 b0 = *(const lng2*)(pB + bBase);
            lng2 b1 = *(const lng2*)(pB + bBase + 1024);
            lng2 b2 = *(const lng2*)(pB + bBase + 2048);
            lng2 b3 = *(const lng2*)(pB + bBase + 3072);
            FP8MFMA(acc[0][0], a0.x, b0.x); FP8MFMA(acc[0][1], a0.x, b1.x);
            FP8MFMA(acc[0][2], a0.x, b2.x); FP8MFMA(acc[0][3], a0.x, b3.x);
            FP8MFMA(acc[1][0], a1.x, b0.x); FP8MFMA(acc[1][1], a1.x, b1.x);
            FP8MFMA(acc[1][2], a1.x, b2.x); FP8MFMA(acc[1][3], a1.x, b3.x);
            FP8MFMA(acc[0][0], a0.y, b0.y); FP8MFMA(acc[0][1], a0.y, b1.y);
            FP8MFMA(acc[0][2], a0.y, b2.y); FP8MFMA(acc[0][3], a0.y, b3.y);
            FP8MFMA(acc[1][0], a1.y, b0.y); FP8MFMA(acc[1][1], a1.y, b1.y);
            FP8MFMA(acc[1][2], a1.y, b2.y); FP8MFMA(acc[1][3], a1.y, b3.y);
        }

        if (tile < 5) {
            // cross-tile: stage(1) into buf1 (read at si==7 by ALL waves ->
            // need my lgkm done + a barrier before the DMA).
            asm volatile("s_waitcnt lgkmcnt(0)" ::: "memory");
            asm volatile("s_barrier" ::: "memory");
            GLD_LDS16(gAx + 64, &sA[1][wave * 1024]);
            GLD_LDS16(gBx + 64, &sB[1][wave * 1024]);
        }

        // ---- slim fused epilogue (verified R7-R30, unchanged); runs with
        //      next tile's 4 staging loads in flight. ----
        const float* tA = times + pa * B_SZ;
        const float* tB = times + pb * B_SZ;
        int rowbase = rowBlk + wr * 32;
        int colbase = colBlk + wc * 64;

        float tb[4]; int lb[4]; int mcol[4];
        #pragma unroll
        for (int j = 0; j < 4; ++j) {
            mcol[j] = colbase + j * 16 + s;
            tb[j] = tB[mcol[j]];
            lb[j] = labels[mcol[j]];
        }
        float colE[4] = {0.f, 0.f, 0.f, 0.f}, colT[4] = {0.f, 0.f, 0.f, 0.f};

        float* rsE = rsum_e + z * B_SZ;
        float* rsT = rsum_t + z * B_SZ;
        float* csE = csum_e + z * B_SZ;
        float* csT = csum_t + z * B_SZ;

        #pragma unroll
        for (int ii = 0; ii < 2; ++ii) {
            int nb = rowbase + ii * 16 + q * 4;   // this lane's 4 C rows
            float cta[4]; int la[4];
            #pragma unroll
            for (int r = 0; r < 4; ++r) { cta[r] = curv * tA[nb + r]; la[r] = labels[nb + r]; }
            float re[4] = {0.f, 0.f, 0.f, 0.f}, rt[4] = {0.f, 0.f, 0.f, 0.f};
            #pragma unroll
            for (int j = 0; j < 4; ++j) {
                floatx4 a = acc[ii][j];
                #pragma unroll
                for (int r = 0; r < 4; ++r) {
                    float zc = fmaf(-curv, a[r], cta[r] * tb[j]);
                    zc = fmaxf(zc, 1.0f + 1e-8f);
                    float lz = __log2f(zc);
                    float e = __builtin_amdgcn_exp2f(fmaf(c2, lz, sh2p));
                    float tl2 = (la[r] == lb[j]) ? fmaf(c1, lz, c1) : 0.0f;
                    re[r] += e; rt[r] += tl2;
                    colE[j] += e; colT[j] += tl2;
                }
            }
            #pragma unroll
            for (int r = 0; r < 4; ++r) {
                #pragma unroll
                for (int m = 1; m <= 8; m <<= 1) {
                    re[r] += __shfl_xor(re[r], m);
                    rt[r] += __shfl_xor(rt[r], m);
                }
            }
            #pragma unroll
            for (int r = 0; r < 4; ++r) {
                if (s == r) {
                    atomicAdd(&rsE[nb + r], re[r]);
                    atomicAdd(&rsT[nb + r], rt[r]);
                }
            }
        }
        #pragma unroll
        for (int j = 0; j < 4; ++j) {
            colE[j] += __shfl_xor(colE[j], 16); colE[j] += __shfl_xor(colE[j], 32);
            colT[j] += __shfl_xor(colT[j], 16); colT[j] += __shfl_xor(colT[j], 32);
            if (q == 0) {
                atomicAdd(&csE[mcol[j]], colE[j]);
                atomicAdd(&csT[mcol[j]], colT[j]);
            }
        }
        // next tile's si=0: lgkmcnt(0) + vmcnt(2) + barrier resync.
    }

    // ---- fused finalize: last of 512 blocks reduces and writes out ----
    // Order own epilogue atomics (VMEM) before joining the done counter.
    asm volatile("s_waitcnt vmcnt(0) lgkmcnt(0)" ::: "memory");
    if (t == 0) last_flag = (atomicAdd(done, 1) == 511) ? 1 : 0;
    __syncthreads();
    if (last_flag) {
        float part = 0.0f;
        #pragma unroll 1
        for (int k = 0; k < 8; ++k) {
            int n = t + k * 512;                      // coalesced over 4096
            float Sn = (float)hist[labels[n]];        // prep-written: plain ok
            #pragma unroll
            for (int p = 0; p < 3; ++p) {
                float rse = atomicAdd(&rsum_e[p * B_SZ + n], 0.0f);
                float rst = atomicAdd(&rsum_t[p * B_SZ + n], 0.0f);
                float cse = atomicAdd(&csum_e[p * B_SZ + n], 0.0f);
                float cst = atomicAdd(&csum_t[p * B_SZ + n], 0.0f);
                part += Sn * (__logf(rse) - SHIFT) - rst;
                part += Sn * (__logf(cse) - SHIFT) - cst;
            }
        }
        float ep = ent_partial[t] + ent_partial[t + 512];   // prep-written
        #pragma unroll
        for (int m = 1; m < 64; m <<= 1) {
            part += __shfl_xor(part, m);
            ep   += __shfl_xor(ep, m);
        }
        if (lane == 0) { fin_red[wave] = part; fin_red2[wave] = ep; }
        __syncthreads();
        if (t == 0) {
            float ce = 0.0f, ent = 0.0f;
            #pragma unroll
            for (int w = 0; w < 8; ++w) { ce += fin_red[w]; ent += fin_red2[w]; }
            float contr = ce / (6.0f * (float)B_SZ);
            ent /= (float)B_SZ;
            out[0] = contr + 0.2f * ent;
            out[1] = contr;
            out[2] = ent;
        }
    }
}

// ---- workspace layout (bytes) ----
//   0       : fp8 feats (K-interleaved), 3*4096*512 = 6,291,456
//   6291456 : times[3][4096] f32   (49,152)
//   6340608 : rsum_e[12288 f]  \
//   6389760 : rsum_t           | zero region: 49155 floats
//   6438912 : csum_e           | (incl. ce_acc, ent_acc, done)
//   6488064 : csum_t           |
//   6537216 : ce_acc f32; 6537220: ent_acc f32; 6537224: done i32
//   6537228 : ent_partial[1024] f32 (every slot written by its dna block)
//   6541324 : hist[512] int (fully written by prep block 0)
extern "C" void kernel_launch(void* const* d_in, const int* in_sizes, int n_in,
                              void* d_out, int out_size, void* d_ws, size_t ws_size,
                              hipStream_t stream) {
    const float* img    = (const float*)d_in[0];
    const float* dna    = (const float*)d_in[1];
    const float* txt    = (const float*)d_in[2];
    const int*   labels = (const int*)d_in[3];
    const float* ls     = (const float*)d_in[4];
    const float* curv   = (const float*)d_in[5];

    char* ws = (char*)d_ws;
    u8*    f8     = (u8*)ws;
    float* times  = (float*)(ws + 6291456);
    float* rsum_e = (float*)(ws + 6340608);
    float* rsum_t = (float*)(ws + 6389760);
    float* csum_e = (float*)(ws + 6438912);
    float* csum_t = (float*)(ws + 6488064);
    int*   done   = (int*)  (ws + 6537224);
    float* ent_p  = (float*)(ws + 6537228);
    int*   hist   = (int*)  (ws + 6541324);

    prep_kernel<<<3072, 256, 0, stream>>>(img, dna, txt, curv, labels, hist,
                                          f8, times, rsum_e, ent_p);
    gemm_epi_kernel<<<512, 512, 0, stream>>>(f8, times, labels, ls, curv,
                                             rsum_e, rsum_t, csum_e, csum_t,
                                             hist, ent_p, done, (float*)d_out);
}

// Round 15
// 151.154 us; speedup vs baseline: 1.0455x; 1.0455x over previous
//
#include <hip/hip_runtime.h>
#include <stdint.h>

#define B_SZ 4096
#define D_SZ 512
#define SHIFT 64.0f

typedef __attribute__((ext_vector_type(4))) float floatx4;
typedef __attribute__((ext_vector_type(2))) long lng2;
typedef unsigned char u8;
typedef unsigned int u32;

#define GLD_LDS16(gp, sp)                                                              \
    __builtin_amdgcn_global_load_lds(                                                  \
        (const __attribute__((address_space(1))) void*)(gp),                           \
        (__attribute__((address_space(3))) void*)(sp), 16, 0, 0)

#define FP8MFMA(accv, av, bv)                                                          \
    accv = __builtin_amdgcn_mfma_f32_16x16x32_fp8_fp8(av, bv, accv, 0, 0, 0)

// ---- K1: fp32->fp8(e4m3) convert (K-interleaved layout) + per-row time,
//      fused: histogram (block 0), accumulator zeroing, entailment partials.
//      K-perm: within each 64B K-window, 8B group (h,c) -> slot c*2+h; applied
//      to BOTH operands => Grammian unchanged. ----
__global__ __launch_bounds__(256) void prep_kernel(
    const float* __restrict__ img, const float* __restrict__ dna,
    const float* __restrict__ txt, const float* __restrict__ curv_p,
    const int* __restrict__ labels, int* __restrict__ hist,
    u8* __restrict__ f8, float* __restrict__ times,
    float* __restrict__ zero_f, float* __restrict__ ent_partial) {
    __shared__ int lhist[512];
    __shared__ float red[4];
    int t = threadIdx.x;
    int gid = blockIdx.x * 256 + t;
    if (gid < 49155) zero_f[gid] = 0.0f;    // rsum/csum + ce_acc/ent_acc/done

    if (blockIdx.x == 0) {                  // label histogram, single block
        lhist[t] = 0; lhist[t + 256] = 0;
        __syncthreads();
        for (int n = t; n < B_SZ; n += 256) atomicAdd(&lhist[labels[n]], 1);
        __syncthreads();
        hist[t] = lhist[t]; hist[t + 256] = lhist[t + 256];
    }

    int wave = gid >> 6;  // 0..12287
    int lane = t & 63;
    const float* src = (wave < B_SZ) ? img : (wave < 2 * B_SZ) ? dna : txt;
    int row = wave & (B_SZ - 1);
    const float* p = src + row * D_SZ + lane * 8;
    float4 v0 = *(const float4*)(p);
    float4 v1 = *(const float4*)(p + 4);
    float ss = v0.x*v0.x + v0.y*v0.y + v0.z*v0.z + v0.w*v0.w
             + v1.x*v1.x + v1.y*v1.y + v1.z*v1.z + v1.w*v1.w;
    u32 w0 = __builtin_amdgcn_cvt_pk_fp8_f32(v0.x, v0.y, 0, false);
    w0 = __builtin_amdgcn_cvt_pk_fp8_f32(v0.z, v0.w, w0, true);
    u32 w1 = __builtin_amdgcn_cvt_pk_fp8_f32(v1.x, v1.y, 0, false);
    w1 = __builtin_amdgcn_cvt_pk_fp8_f32(v1.z, v1.w, w1, true);
    uint2 pk; pk.x = w0; pk.y = w1;
    // lane = 8B group: window lane>>3, half (lane>>2)&1, chunk lane&3
    int gperm = (lane & 56) | ((lane & 3) << 1) | ((lane >> 2) & 1);
    *(uint2*)(f8 + (size_t)wave * D_SZ + gperm * 8) = pk;

    bool isdna = (wave >= B_SZ) && (wave < 2 * B_SZ);
    float dot = 0.0f, ssy = 0.0f;
    if (isdna) {                            // matching image row for entailment
        const float* y = img + row * D_SZ + lane * 8;
        float4 y0 = *(const float4*)y, y1 = *(const float4*)(y + 4);
        dot = v0.x*y0.x + v0.y*y0.y + v0.z*y0.z + v0.w*y0.w
            + v1.x*y1.x + v1.y*y1.y + v1.z*y1.z + v1.w*y1.w;
        ssy = y0.x*y0.x + y0.y*y0.y + y0.z*y0.z + y0.w*y0.w
            + y1.x*y1.x + y1.y*y1.y + y1.z*y1.z + y1.w*y1.w;
    }
    #pragma unroll
    for (int m = 1; m < 64; m <<= 1) {
        ss += __shfl_xor(ss, m);
        if (isdna) { dot += __shfl_xor(dot, m); ssy += __shfl_xor(ssy, m); }
    }
    float curv = curv_p[0];
    float ep = 0.0f;
    if (lane == 0) {
        float xt = sqrtf(1.0f / curv + ss);
        times[wave] = xt;
        if (isdna) {
            float yt = sqrtf(1.0f / curv + ssy);
            float nx = sqrtf(ss);
            float c = curv * (dot - xt * yt);                      // <= -1
            float numer = yt + c * xt;
            float denom = nx * sqrtf(fmaxf(c * c - 1.0f, 0.0f));
            float ai = numer / (denom + 1e-8f);
            ai = fminf(fmaxf(ai, -1.0f + 1e-8f), 1.0f - 1e-8f);
            float ang = acosf(ai);
            float as_in = 0.2f / (nx * sqrtf(curv) + 1e-6f);       // 2*min_radius
            as_in = fminf(fmaxf(as_in, -1.0f + 1e-6f), 1.0f - 1e-6f);
            float ap = asinf(as_in);
            ep = fmaxf(ang - ap, 0.0f);
        }
    }
    if (blockIdx.x >= 1024 && blockIdx.x < 2048) {   // pure-dna blocks
        if (lane == 0) red[t >> 6] = ep;
        __syncthreads();
        if (t == 0) ent_partial[blockIdx.x - 1024] = red[0] + red[1] + red[2] + red[3];
    }
}

// ---- K2: batched fp8 MFMA GEMM (A·B^T), 128x128 tile, 8 waves, 32x64/wave.
//      R32 = R30 CHAMPION, restored verbatim (gemm 77us, total 150.0).
//      R31's fused finalize REGRESSED (total 158, gemm dispatch 83.8,
//      occ 38.9->32.3): end-of-kernel vmcnt(0)+done-atomic serializes block
//      retirement, and the last block's finalize is a serial tail inside
//      the dispatch where the separate 16-block kernel ran wide. Fusion of
//      a dependent reduction into a persistent producer = net loss here.
//      Structure: 512 blocks (exact 2/CU residency), 6 consecutive linear
//      tiles each; R24 in-tile schedule (counted-vmcnt dist-2, 1 barrier
//      per K-step, no setprio); cross-tile pipelining: next tile's stage(0)
//      at si==7 post-barrier (buf0 last read si==6 -> safe), stage(1)
//      post-loop after lgkmcnt(0)+barrier (buf1 read si==7 -> safe);
//      epilogue runs with 4 staging loads in flight.
//      vmcnt ledger (2 GLD/stage -- per-geometry, ALWAYS re-derive): si in
//      [0,6] top: in-flight = stage(si)+stage(si+1) = 4 -> vmcnt(2) awaits
//      stage(si); si==7: vmcnt(0). R29's vmcnt(4) transcription bug = race.
//      Ledger: R31 fused finalize regressed (158). R30 = 150.0 (champion).
//      R29 ledger bug. R28/R19 256^2 spill (allocator pins 128 VGPR at
//      512thr; dead family). R27 256thr VGPR pin -> occ 19.7%. R26 reg-dbuf
//      spill. R25 dist-3+setprio regressed. R24 = 88.5 single-shot. R23 XCD
//      remap regressed. R22 direct-L2 regressed (GEMM needs LDS reuse).
//      R20 4-phase +10% cost. R18 min-waves pin spill. R15 per-block
//      threadfence storm. Non-gemm ~73us: prep ~12, finalize ~3, rest
//      harness launch/reset overhead (R31 proved fusion can't buy it back).
__global__ __launch_bounds__(512, 4) void gemm_epi_kernel(
    const u8* __restrict__ f8, const float* __restrict__ times,
    const int* __restrict__ labels,
    const float* __restrict__ ls_p, const float* __restrict__ curv_p,
    float* __restrict__ rsum_e, float* __restrict__ rsum_t,
    float* __restrict__ csum_e, float* __restrict__ csum_t) {
    __shared__ u8 sA[3][128 * 64];    // 24 KB
    __shared__ u8 sB[3][128 * 64];    // 24 KB -> 48 KB total, 2 blocks/CU

    int t = threadIdx.x;
    int wave = t >> 6, lane = t & 63;
    int wr = wave >> 1;                   // row 32-group (0..3)
    int wc = wave & 1;                    // col 64-group (0..1)
    int chunk = (t & 3) ^ ((t >> 3) & 3);
    int q = lane >> 4, s = lane & 15;
    int slot16 = (q ^ ((s >> 1) & 3)) << 4;
    int aBase = (wr * 32 + s) * 64 + slot16;     // + ii*1024 per fragment
    int bBase = (wc * 64 + s) * 64 + slot16;     // + j*1024 per fragment

    float ls = ls_p[0];
    float curv = curv_p[0];
    float rsc = rsqrtf(curv);
    float c2 = -ls * rsc;
    float c1 = c2 * 0.69314718f;
    float sh2p = SHIFT * 1.44269504f + c2;

    const u8* gA = nullptr;  const u8* gB = nullptr;

    #pragma unroll 1
    for (int tile = 0; tile < 6; ++tile) {
        int tl  = blockIdx.x * 6 + tile;          // 0..3071
        int z   = tl >> 10;                       // 0:(img,dna) 1:(img,txt) 2:(dna,txt)
        int rem = tl & 1023;
        int rowBlk = (rem >> 5) * 128;
        int colBlk = (rem & 31) * 128;
        int pa = (z == 2) ? 1 : 0;
        int pb = (z == 0) ? 1 : 2;
        const u8* A  = f8 + (size_t)pa * (B_SZ * D_SZ);
        const u8* Bm = f8 + (size_t)pb * (B_SZ * D_SZ);
        // Staging ptrs (R21/R24-verified mapping): thread t -> row t>>2,
        // global chunk (t&3)^((t>>3)&3); LDS linear => involution swizzle.
        const u8* gA_n = A  + (size_t)(rowBlk + (t >> 2)) * D_SZ + chunk * 16;
        const u8* gB_n = Bm + (size_t)(colBlk + (t >> 2)) * D_SZ + chunk * 16;

        if (tile == 0) {
            // cold prologue: stage K-steps 0,1 into buffers 0,1
            GLD_LDS16(gA_n,      &sA[0][wave * 1024]);
            GLD_LDS16(gB_n,      &sB[0][wave * 1024]);
            GLD_LDS16(gA_n + 64, &sA[1][wave * 1024]);
            GLD_LDS16(gB_n + 64, &sB[1][wave * 1024]);
        }
        // (for tile>0, stage(0)/stage(1) were issued during the previous
        //  tile's si==7 body and pre-epilogue, using gAx/gBx)
        gA = gA_n; gB = gB_n;

        floatx4 acc[2][4];
        #pragma unroll
        for (int ii = 0; ii < 2; ++ii)
            #pragma unroll
            for (int j = 0; j < 4; ++j) acc[ii][j] = (floatx4){0.f, 0.f, 0.f, 0.f};

        // next-tile staging ptrs (used only when tile<5)
        int tln  = tl + 1;
        int zn   = tln >> 10;
        int remn = tln & 1023;
        const u8* An  = f8 + (size_t)((zn == 2) ? 1 : 0) * (B_SZ * D_SZ);
        const u8* Bn  = f8 + (size_t)((zn == 0) ? 1 : 2) * (B_SZ * D_SZ);
        const u8* gAx = An + (size_t)(((remn >> 5) * 128) + (t >> 2)) * D_SZ + chunk * 16;
        const u8* gBx = Bn + (size_t)(((remn & 31) * 128) + (t >> 2)) * D_SZ + chunk * 16;

        #pragma unroll
        for (int si = 0; si < D_SZ / 64; ++si) {
            const int cur = si % 3;
            // own prior-step ds_reads consumed before the barrier (buffer-
            // reuse safety for the distance-2 DMA target); then wait ONLY
            // stage(si): in-flight = stage(si)+stage(si+1) = 4 -> vmcnt(2).
            asm volatile("s_waitcnt lgkmcnt(0)" ::: "memory");
            if (si < 7) { asm volatile("s_waitcnt vmcnt(2)" ::: "memory"); }
            else        { asm volatile("s_waitcnt vmcnt(0)" ::: "memory"); }
            asm volatile("s_barrier" ::: "memory");
            if (si < 6) {
                // prefetch distance 2: stage(si+2) into buf[(si+2)%3]
                // (= buf[(si-1)%3], fully read before barrier(si)).
                const int nxb = (si + 2) % 3;
                const int ko  = (si + 2) * 64;
                GLD_LDS16(gA + ko, &sA[nxb][wave * 1024]);
                GLD_LDS16(gB + ko, &sB[nxb][wave * 1024]);
            } else if (si == 7 && tile < 5) {
                // cross-tile: next tile's stage(0) into buf0 (last read at
                // si==6; all waves past barrier(7) -> safe).
                GLD_LDS16(gAx, &sA[0][wave * 1024]);
                GLD_LDS16(gBx, &sB[0][wave * 1024]);
            }
            const u8* pA = &sA[cur][0];
            const u8* pB = &sB[cur][0];
            lng2 a0 = *(const lng2*)(pA + aBase);
            lng2 a1 = *(const lng2*)(pA + aBase + 1024);
            lng2 b0 = *(const lng2*)(pB + bBase);
            lng2 b1 = *(const lng2*)(pB + bBase + 1024);
            lng2 b2 = *(const lng2*)(pB + bBase + 2048);
            lng2 b3 = *(const lng2*)(pB + bBase + 3072);
            FP8MFMA(acc[0][0], a0.x, b0.x); FP8MFMA(acc[0][1], a0.x, b1.x);
            FP8MFMA(acc[0][2], a0.x, b2.x); FP8MFMA(acc[0][3], a0.x, b3.x);
            FP8MFMA(acc[1][0], a1.x, b0.x); FP8MFMA(acc[1][1], a1.x, b1.x);
            FP8MFMA(acc[1][2], a1.x, b2.x); FP8MFMA(acc[1][3], a1.x, b3.x);
            FP8MFMA(acc[0][0], a0.y, b0.y); FP8MFMA(acc[0][1], a0.y, b1.y);
            FP8MFMA(acc[0][2], a0.y, b2.y); FP8MFMA(acc[0][3], a0.y, b3.y);
            FP8MFMA(acc[1][0], a1.y, b0.y); FP8MFMA(acc[1][1], a1.y, b1.y);
            FP8MFMA(acc[1][2], a1.y, b2.y); FP8MFMA(acc[1][3], a1.y, b3.y);
        }

        if (tile < 5) {
            // cross-tile: stage(1) into buf1 (read at si==7 by ALL waves ->
            // need my lgkm done + a barrier before the DMA).
            asm volatile("s_waitcnt lgkmcnt(0)" ::: "memory");
            asm volatile("s_barrier" ::: "memory");
            GLD_LDS16(gAx + 64, &sA[1][wave * 1024]);
            GLD_LDS16(gBx + 64, &sB[1][wave * 1024]);
        }

        // ---- slim fused epilogue (verified R7-R30, unchanged); runs with
        //      next tile's 4 staging loads in flight. ----
        const float* tA = times + pa * B_SZ;
        const float* tB = times + pb * B_SZ;
        int rowbase = rowBlk + wr * 32;
        int colbase = colBlk + wc * 64;

        float tb[4]; int lb[4]; int mcol[4];
        #pragma unroll
        for (int j = 0; j < 4; ++j) {
            mcol[j] = colbase + j * 16 + s;
            tb[j] = tB[mcol[j]];
            lb[j] = labels[mcol[j]];
        }
        float colE[4] = {0.f, 0.f, 0.f, 0.f}, colT[4] = {0.f, 0.f, 0.f, 0.f};

        float* rsE = rsum_e + z * B_SZ;
        float* rsT = rsum_t + z * B_SZ;
        float* csE = csum_e + z * B_SZ;
        float* csT = csum_t + z * B_SZ;

        #pragma unroll
        for (int ii = 0; ii < 2; ++ii) {
            int nb = rowbase + ii * 16 + q * 4;   // this lane's 4 C rows
            float cta[4]; int la[4];
            #pragma unroll
            for (int r = 0; r < 4; ++r) { cta[r] = curv * tA[nb + r]; la[r] = labels[nb + r]; }
            float re[4] = {0.f, 0.f, 0.f, 0.f}, rt[4] = {0.f, 0.f, 0.f, 0.f};
            #pragma unroll
            for (int j = 0; j < 4; ++j) {
                floatx4 a = acc[ii][j];
                #pragma unroll
                for (int r = 0; r < 4; ++r) {
                    float zc = fmaf(-curv, a[r], cta[r] * tb[j]);
                    zc = fmaxf(zc, 1.0f + 1e-8f);
                    float lz = __log2f(zc);
                    float e = __builtin_amdgcn_exp2f(fmaf(c2, lz, sh2p));
                    float tl2 = (la[r] == lb[j]) ? fmaf(c1, lz, c1) : 0.0f;
                    re[r] += e; rt[r] += tl2;
                    colE[j] += e; colT[j] += tl2;
                }
            }
            #pragma unroll
            for (int r = 0; r < 4; ++r) {
                #pragma unroll
                for (int m = 1; m <= 8; m <<= 1) {
                    re[r] += __shfl_xor(re[r], m);
                    rt[r] += __shfl_xor(rt[r], m);
                }
            }
            #pragma unroll
            for (int r = 0; r < 4; ++r) {
                if (s == r) {
                    atomicAdd(&rsE[nb + r], re[r]);
                    atomicAdd(&rsT[nb + r], rt[r]);
                }
            }
        }
        #pragma unroll
        for (int j = 0; j < 4; ++j) {
            colE[j] += __shfl_xor(colE[j], 16); colE[j] += __shfl_xor(colE[j], 32);
            colT[j] += __shfl_xor(colT[j], 16); colT[j] += __shfl_xor(colT[j], 32);
            if (q == 0) {
                atomicAdd(&csE[mcol[j]], colE[j]);
                atomicAdd(&csT[mcol[j]], colT[j]);
            }
        }
        // next tile's si=0: lgkmcnt(0) + vmcnt(2) + barrier resync.
    }
}

// ---- parallel finalize: 16 blocks, device-scope atomic accumulation; last
//      block (done counter) writes out. atomicAdd(p,0) read avoids stale L2. ----
__global__ __launch_bounds__(256) void finalize_kernel(
    const float* __restrict__ rsum_e, const float* __restrict__ rsum_t,
    const float* __restrict__ csum_e, const float* __restrict__ csum_t,
    const int* __restrict__ labels, const int* __restrict__ hist,
    const float* __restrict__ ent_partial,
    float* __restrict__ ce_acc, float* __restrict__ ent_acc,
    int* __restrict__ done, float* __restrict__ out) {
    __shared__ float red[4], red2[4];
    int b = blockIdx.x, tid = threadIdx.x;
    int n = b * 256 + tid;                 // covers 0..4095 exactly
    float Sn = (float)hist[labels[n]];
    float part = 0.0f;
    #pragma unroll
    for (int p = 0; p < 3; ++p) {
        part += Sn * (__logf(rsum_e[p * B_SZ + n]) - SHIFT) - rsum_t[p * B_SZ + n];
        part += Sn * (__logf(csum_e[p * B_SZ + n]) - SHIFT) - csum_t[p * B_SZ + n];
    }
    float ep = (b < 4) ? ent_partial[b * 256 + tid] : 0.0f;
    #pragma unroll
    for (int m = 1; m < 64; m <<= 1) {
        part += __shfl_xor(part, m);
        ep   += __shfl_xor(ep, m);
    }
    if ((tid & 63) == 0) { red[tid >> 6] = part; red2[tid >> 6] = ep; }
    __syncthreads();
    if (tid == 0) {
        atomicAdd(ce_acc, red[0] + red[1] + red[2] + red[3]);
        atomicAdd(ent_acc, red2[0] + red2[1] + red2[2] + red2[3]);
        __threadfence();
        if (atomicAdd(done, 1) == 15) {        // last of 16 blocks
            float ce = atomicAdd(ce_acc, 0.0f);    // coherent read
            float ent = atomicAdd(ent_acc, 0.0f);
            float contr = ce / (6.0f * (float)B_SZ);
            ent /= (float)B_SZ;
            out[0] = contr + 0.2f * ent;
            out[1] = contr;
            out[2] = ent;
        }
    }
}

// ---- workspace layout (bytes) ----
//   0       : fp8 feats (K-interleaved), 3*4096*512 = 6,291,456
//   6291456 : times[3][4096] f32   (49,152)
//   6340608 : rsum_e[12288 f]  \
//   6389760 : rsum_t           | zero region: 49155 floats
//   6438912 : csum_e           | (incl. ce_acc, ent_acc, done)
//   6488064 : csum_t           |
//   6537216 : ce_acc f32; 6537220: ent_acc f32; 6537224: done i32
//   6537228 : ent_partial[1024] f32 (every slot written by its dna block)
//   6541324 : hist[512] int (fully written by prep block 0)
extern "C" void kernel_launch(void* const* d_in, const int* in_sizes, int n_in,
                              void* d_out, int out_size, void* d_ws, size_t ws_size,
                              hipStream_t stream) {
    const float* img    = (const float*)d_in[0];
    const float* dna    = (const float*)d_in[1];
    const float* txt    = (const float*)d_in[2];
    const int*   labels = (const int*)d_in[3];
    const float* ls     = (const float*)d_in[4];
    const float* curv   = (const float*)d_in[5];

    char* ws = (char*)d_ws;
    u8*    f8     = (u8*)ws;
    float* times  = (float*)(ws + 6291456);
    float* rsum_e = (float*)(ws + 6340608);
    float* rsum_t = (float*)(ws + 6389760);
    float* csum_e = (float*)(ws + 6438912);
    float* csum_t = (float*)(ws + 6488064);
    float* ce_acc = (float*)(ws + 6537216);
    float* ent_acc= (float*)(ws + 6537220);
    int*   done   = (int*)  (ws + 6537224);
    float* ent_p  = (float*)(ws + 6537228);
    int*   hist   = (int*)  (ws + 6541324);

    prep_kernel<<<3072, 256, 0, stream>>>(img, dna, txt, curv, labels, hist,
                                          f8, times, rsum_e, ent_p);
    gemm_epi_kernel<<<512, 512, 0, stream>>>(f8, times, labels, ls, curv,
                                             rsum_e, rsum_t, csum_e, csum_t);
    finalize_kernel<<<16, 256, 0, stream>>>(rsum_e, rsum_t, csum_e, csum_t,
                                            labels, hist, ent_p,
                                            ce_acc, ent_acc, done, (float*)d_out);
}

// Round 16
// 148.325 us; speedup vs baseline: 1.0654x; 1.0191x over previous
//
#include <hip/hip_runtime.h>
#include <stdint.h>

#define B_SZ 4096
#define D_SZ 512
#define SHIFT 64.0f

typedef __attribute__((ext_vector_type(4))) float floatx4;
typedef __attribute__((ext_vector_type(2))) long lng2;
typedef unsigned char u8;
typedef unsigned int u32;

#define GLD_LDS16(gp, sp)                                                              \
    __builtin_amdgcn_global_load_lds(                                                  \
        (const __attribute__((address_space(1))) void*)(gp),                           \
        (__attribute__((address_space(3))) void*)(sp), 16, 0, 0)

#define FP8MFMA(accv, av, bv)                                                          \
    accv = __builtin_amdgcn_mfma_f32_16x16x32_fp8_fp8(av, bv, accv, 0, 0, 0)

// ---- K1: fp32->fp8(e4m3) convert (K-interleaved layout) + per-row time,
//      fused: histogram (block 0), accumulator zeroing, entailment partials.
//      K-perm: within each 64B K-window, 8B group (h,c) -> slot c*2+h; applied
//      to BOTH operands => Grammian unchanged. ----
__global__ __launch_bounds__(256) void prep_kernel(
    const float* __restrict__ img, const float* __restrict__ dna,
    const float* __restrict__ txt, const float* __restrict__ curv_p,
    const int* __restrict__ labels, int* __restrict__ hist,
    u8* __restrict__ f8, float* __restrict__ times,
    float* __restrict__ zero_f, float* __restrict__ ent_partial) {
    __shared__ int lhist[512];
    __shared__ float red[4];
    int t = threadIdx.x;
    int gid = blockIdx.x * 256 + t;
    if (gid < 49155) zero_f[gid] = 0.0f;    // rsum/csum + ce_acc/ent_acc/done

    if (blockIdx.x == 0) {                  // label histogram, single block
        lhist[t] = 0; lhist[t + 256] = 0;
        __syncthreads();
        for (int n = t; n < B_SZ; n += 256) atomicAdd(&lhist[labels[n]], 1);
        __syncthreads();
        hist[t] = lhist[t]; hist[t + 256] = lhist[t + 256];
    }

    int wave = gid >> 6;  // 0..12287
    int lane = t & 63;
    const float* src = (wave < B_SZ) ? img : (wave < 2 * B_SZ) ? dna : txt;
    int row = wave & (B_SZ - 1);
    const float* p = src + row * D_SZ + lane * 8;
    float4 v0 = *(const float4*)(p);
    float4 v1 = *(const float4*)(p + 4);
    float ss = v0.x*v0.x + v0.y*v0.y + v0.z*v0.z + v0.w*v0.w
             + v1.x*v1.x + v1.y*v1.y + v1.z*v1.z + v1.w*v1.w;
    u32 w0 = __builtin_amdgcn_cvt_pk_fp8_f32(v0.x, v0.y, 0, false);
    w0 = __builtin_amdgcn_cvt_pk_fp8_f32(v0.z, v0.w, w0, true);
    u32 w1 = __builtin_amdgcn_cvt_pk_fp8_f32(v1.x, v1.y, 0, false);
    w1 = __builtin_amdgcn_cvt_pk_fp8_f32(v1.z, v1.w, w1, true);
    uint2 pk; pk.x = w0; pk.y = w1;
    // lane = 8B group: window lane>>3, half (lane>>2)&1, chunk lane&3
    int gperm = (lane & 56) | ((lane & 3) << 1) | ((lane >> 2) & 1);
    *(uint2*)(f8 + (size_t)wave * D_SZ + gperm * 8) = pk;

    bool isdna = (wave >= B_SZ) && (wave < 2 * B_SZ);
    float dot = 0.0f, ssy = 0.0f;
    if (isdna) {                            // matching image row for entailment
        const float* y = img + row * D_SZ + lane * 8;
        float4 y0 = *(const float4*)y, y1 = *(const float4*)(y + 4);
        dot = v0.x*y0.x + v0.y*y0.y + v0.z*y0.z + v0.w*y0.w
            + v1.x*y1.x + v1.y*y1.y + v1.z*y1.z + v1.w*y1.w;
        ssy = y0.x*y0.x + y0.y*y0.y + y0.z*y0.z + y0.w*y0.w
            + y1.x*y1.x + y1.y*y1.y + y1.z*y1.z + y1.w*y1.w;
    }
    #pragma unroll
    for (int m = 1; m < 64; m <<= 1) {
        ss += __shfl_xor(ss, m);
        if (isdna) { dot += __shfl_xor(dot, m); ssy += __shfl_xor(ssy, m); }
    }
    float curv = curv_p[0];
    float ep = 0.0f;
    if (lane == 0) {
        float xt = sqrtf(1.0f / curv + ss);
        times[wave] = xt;
        if (isdna) {
            float yt = sqrtf(1.0f / curv + ssy);
            float nx = sqrtf(ss);
            float c = curv * (dot - xt * yt);                      // <= -1
            float numer = yt + c * xt;
            float denom = nx * sqrtf(fmaxf(c * c - 1.0f, 0.0f));
            float ai = numer / (denom + 1e-8f);
            ai = fminf(fmaxf(ai, -1.0f + 1e-8f), 1.0f - 1e-8f);
            float ang = acosf(ai);
            float as_in = 0.2f / (nx * sqrtf(curv) + 1e-6f);       // 2*min_radius
            as_in = fminf(fmaxf(as_in, -1.0f + 1e-6f), 1.0f - 1e-6f);
            float ap = asinf(as_in);
            ep = fmaxf(ang - ap, 0.0f);
        }
    }
    if (blockIdx.x >= 1024 && blockIdx.x < 2048) {   // pure-dna blocks
        if (lane == 0) red[t >> 6] = ep;
        __syncthreads();
        if (t == 0) ent_partial[blockIdx.x - 1024] = red[0] + red[1] + red[2] + red[3];
    }
}

// ---- K2: batched fp8 MFMA GEMM (A·B^T), 128x128 tile, 8 waves, 32x64/wave.
//      R33 = R32 persistent champion (gemm 76.5us, total 150-151) + READ-
//      AHEAD register pipeline: at step k, await stage(k+1), issue stage
//      (k+3) [dist-3, 4 buffers], read frags(k+1) into the ALTERNATE named
//      register set, MFMA on the current set -- the 6 ds_read_b128 (+~120cy
//      latency) move off the critical path under the 16-MFMA cluster.
//      R26 tried this pre-persistent and SPILLED (frag arrays -> scratch,
//      WRITE 48MB); fix per rule #20: NAMED register sets via token-pasting
//      macro (eA0.. / oA0..), zero indexed arrays.
//      Globally uniform schedule (stage(k) issued at step k-3; k = tile*8+si):
//        si=0..4: issue current-tile stage(si+3) -> buf[(si+3)&3]
//        si=5,6,7: issue NEXT-tile stage(0,1,2) -> buf[0,1,2]  (tile<5)
//        read-ahead at si reads buf[(si+1)&3]; si=7 reads next tile frags(0)
//      vmcnt ledger (2 GLD/stage, re-derived -- R29 lesson): steady in-flight
//      at step top = {k+1,k+2} = 4 -> vmcnt(2) awaits stage(k+1) (in-order
//      oldest-first, m135). Tile5 tail: si=6 in-flight {47} -> vmcnt(0);
//      si=7 none -> vmcnt(0) no-op, no read-ahead. Prologue: stages 0,1,2
//      (6 loads), vmcnt(4) = stage0 landed, barrier, read frags(0) -> E set.
//      Buffer safety: stage(k+3)->buf[(si+3)&3] last READ at step si-2
//      (read-ahead of frags(si-1)); two barriers of separation + lgkmcnt(0)
//      at each step top. Epilogue VMEM ages before next-tile vmcnt(2)
//      (oldest-first wait covers all stages; over-waits newest 2 epi ops).
//      VALIDITY GATE: WRITE_SIZE must stay ~36.9 MB (R26's spill showed as
//      48 MB). If ballooned -> revert to R32.
//      Ledger: R32=R30 champion 150-151 (gemm 76.5). R31 fused finalize
//      regressed (serial tail). R29 vmcnt transcription bug. R28/R19 256^2
//      spill (dead). R27 256thr VGPR pin. R26 reg-dbuf spill (this round's
//      target, fixed). R25 dist-3+setprio bundle regressed (confounded).
//      R24 counted-vmcnt dist-2 win. R23/R22/R20/R18/R15 regressions.
__global__ __launch_bounds__(512, 4) void gemm_epi_kernel(
    const u8* __restrict__ f8, const float* __restrict__ times,
    const int* __restrict__ labels,
    const float* __restrict__ ls_p, const float* __restrict__ curv_p,
    float* __restrict__ rsum_e, float* __restrict__ rsum_t,
    float* __restrict__ csum_e, float* __restrict__ csum_t) {
    __shared__ u8 sA[4][128 * 64];    // 32 KB
    __shared__ u8 sB[4][128 * 64];    // 32 KB -> 64 KB total, 2 blocks/CU

    int t = threadIdx.x;
    int wave = t >> 6, lane = t & 63;
    int wr = wave >> 1;                   // row 32-group (0..3)
    int wc = wave & 1;                    // col 64-group (0..1)
    int chunk = (t & 3) ^ ((t >> 3) & 3);
    int q = lane >> 4, s = lane & 15;
    int slot16 = (q ^ ((s >> 1) & 3)) << 4;
    int aBase = (wr * 32 + s) * 64 + slot16;     // + ii*1024 per fragment
    int bBase = (wc * 64 + s) * 64 + slot16;     // + j*1024 per fragment

    float ls = ls_p[0];
    float curv = curv_p[0];
    float rsc = rsqrtf(curv);
    float c2 = -ls * rsc;
    float c1 = c2 * 0.69314718f;
    float sh2p = SHIFT * 1.44269504f + c2;

    // named frag register sets (rule #20: no indexed arrays -> no scratch)
    lng2 eA0, eA1, eB0, eB1, eB2, eB3;    // even-step set
    lng2 oA0, oA1, oB0, oB1, oB2, oB3;    // odd-step set

#define TILE_PTRS(TL, GAV, GBV)                                                        \
    {                                                                                  \
        int z_ = (TL) >> 10;                                                           \
        int rem_ = (TL) & 1023;                                                        \
        int pa_ = (z_ == 2) ? 1 : 0;                                                   \
        int pb_ = (z_ == 0) ? 1 : 2;                                                   \
        GAV = f8 + (size_t)pa_ * (B_SZ * D_SZ)                                         \
            + (size_t)(((rem_ >> 5) * 128) + (t >> 2)) * D_SZ + chunk * 16;            \
        GBV = f8 + (size_t)pb_ * (B_SZ * D_SZ)                                         \
            + (size_t)(((rem_ & 31) * 128) + (t >> 2)) * D_SZ + chunk * 16;            \
    }

#define KSTEP(SI, CUR, NXT, ISSUE_COND, PTRA, PTRB, VW2, DO_READ)                      \
    do {                                                                               \
        asm volatile("s_waitcnt lgkmcnt(0)" ::: "memory");                             \
        if (VW2) { asm volatile("s_waitcnt vmcnt(2)" ::: "memory"); }                  \
        else     { asm volatile("s_waitcnt vmcnt(0)" ::: "memory"); }                  \
        asm volatile("s_barrier" ::: "memory");                                        \
        if (ISSUE_COND) {                                                              \
            GLD_LDS16((PTRA), &sA[(SI + 3) & 3][wave * 1024]);                         \
            GLD_LDS16((PTRB), &sB[(SI + 3) & 3][wave * 1024]);                         \
        }                                                                              \
        if (DO_READ) {                                                                 \
            const u8* pA_ = &sA[(SI + 1) & 3][0];                                      \
            const u8* pB_ = &sB[(SI + 1) & 3][0];                                      \
            NXT##A0 = *(const lng2*)(pA_ + aBase);                                     \
            NXT##A1 = *(const lng2*)(pA_ + aBase + 1024);                              \
            NXT##B0 = *(const lng2*)(pB_ + bBase);                                     \
            NXT##B1 = *(const lng2*)(pB_ + bBase + 1024);                              \
            NXT##B2 = *(const lng2*)(pB_ + bBase + 2048);                              \
            NXT##B3 = *(const lng2*)(pB_ + bBase + 3072);                              \
        }                                                                              \
        FP8MFMA(acc[0][0], CUR##A0.x, CUR##B0.x);                                      \
        FP8MFMA(acc[0][1], CUR##A0.x, CUR##B1.x);                                      \
        FP8MFMA(acc[0][2], CUR##A0.x, CUR##B2.x);                                      \
        FP8MFMA(acc[0][3], CUR##A0.x, CUR##B3.x);                                      \
        FP8MFMA(acc[1][0], CUR##A1.x, CUR##B0.x);                                      \
        FP8MFMA(acc[1][1], CUR##A1.x, CUR##B1.x);                                      \
        FP8MFMA(acc[1][2], CUR##A1.x, CUR##B2.x);                                      \
        FP8MFMA(acc[1][3], CUR##A1.x, CUR##B3.x);                                      \
        FP8MFMA(acc[0][0], CUR##A0.y, CUR##B0.y);                                      \
        FP8MFMA(acc[0][1], CUR##A0.y, CUR##B1.y);                                      \
        FP8MFMA(acc[0][2], CUR##A0.y, CUR##B2.y);                                      \
        FP8MFMA(acc[0][3], CUR##A0.y, CUR##B3.y);                                      \
        FP8MFMA(acc[1][0], CUR##A1.y, CUR##B0.y);                                      \
        FP8MFMA(acc[1][1], CUR##A1.y, CUR##B1.y);                                      \
        FP8MFMA(acc[1][2], CUR##A1.y, CUR##B2.y);                                      \
        FP8MFMA(acc[1][3], CUR##A1.y, CUR##B3.y);                                      \
    } while (0)

    // ---- prologue (tile 0): stage K-steps 0,1,2; read frags(0) -> E ----
    const u8* gA;  const u8* gB;
    TILE_PTRS(blockIdx.x * 6, gA, gB);
    GLD_LDS16(gA,       &sA[0][wave * 1024]);
    GLD_LDS16(gB,       &sB[0][wave * 1024]);
    GLD_LDS16(gA + 64,  &sA[1][wave * 1024]);
    GLD_LDS16(gB + 64,  &sB[1][wave * 1024]);
    GLD_LDS16(gA + 128, &sA[2][wave * 1024]);
    GLD_LDS16(gB + 128, &sB[2][wave * 1024]);
    asm volatile("s_waitcnt vmcnt(4)" ::: "memory");   // stage(0) landed
    asm volatile("s_barrier" ::: "memory");
    eA0 = *(const lng2*)(&sA[0][0] + aBase);
    eA1 = *(const lng2*)(&sA[0][0] + aBase + 1024);
    eB0 = *(const lng2*)(&sB[0][0] + bBase);
    eB1 = *(const lng2*)(&sB[0][0] + bBase + 1024);
    eB2 = *(const lng2*)(&sB[0][0] + bBase + 2048);
    eB3 = *(const lng2*)(&sB[0][0] + bBase + 3072);

    #pragma unroll 1
    for (int tile = 0; tile < 6; ++tile) {
        int tl = blockIdx.x * 6 + tile;           // 0..3071
        int z   = tl >> 10;
        int rem = tl & 1023;
        int rowBlk = (rem >> 5) * 128;
        int colBlk = (rem & 31) * 128;
        int pa = (z == 2) ? 1 : 0;
        int pb = (z == 0) ? 1 : 2;
        TILE_PTRS(tl, gA, gB);
        const u8* gAx;  const u8* gBx;            // next tile (guarded by nt)
        TILE_PTRS((tl + 1 < 3072) ? (tl + 1) : 0, gAx, gBx);
        bool nt = (tile < 5);

        floatx4 acc[2][4];
        #pragma unroll
        for (int ii = 0; ii < 2; ++ii)
            #pragma unroll
            for (int j = 0; j < 4; ++j) acc[ii][j] = (floatx4){0.f, 0.f, 0.f, 0.f};

        KSTEP(0, e, o, true, gA + 3 * 64, gB + 3 * 64, true, true);
        KSTEP(1, o, e, true, gA + 4 * 64, gB + 4 * 64, true, true);
        KSTEP(2, e, o, true, gA + 5 * 64, gB + 5 * 64, true, true);
        KSTEP(3, o, e, true, gA + 6 * 64, gB + 6 * 64, true, true);
        KSTEP(4, e, o, true, gA + 7 * 64, gB + 7 * 64, true, true);
        KSTEP(5, o, e, nt,   gAx,         gBx,         true, true);
        KSTEP(6, e, o, nt,   gAx + 64,    gBx + 64,    nt,   true);
        KSTEP(7, o, e, nt,   gAx + 128,   gBx + 128,   nt,   nt);

        // ---- slim fused epilogue (verified R7-R32, unchanged); runs with
        //      next tile's staging loads in flight. ----
        const float* tA = times + pa * B_SZ;
        const float* tB = times + pb * B_SZ;
        int rowbase = rowBlk + wr * 32;
        int colbase = colBlk + wc * 64;

        float tb[4]; int lb[4]; int mcol[4];
        #pragma unroll
        for (int j = 0; j < 4; ++j) {
            mcol[j] = colbase + j * 16 + s;
            tb[j] = tB[mcol[j]];
            lb[j] = labels[mcol[j]];
        }
        float colE[4] = {0.f, 0.f, 0.f, 0.f}, colT[4] = {0.f, 0.f, 0.f, 0.f};

        float* rsE = rsum_e + z * B_SZ;
        float* rsT = rsum_t + z * B_SZ;
        float* csE = csum_e + z * B_SZ;
        float* csT = csum_t + z * B_SZ;

        #pragma unroll
        for (int ii = 0; ii < 2; ++ii) {
            int nb = rowbase + ii * 16 + q * 4;   // this lane's 4 C rows
            float cta[4]; int la[4];
            #pragma unroll
            for (int r = 0; r < 4; ++r) { cta[r] = curv * tA[nb + r]; la[r] = labels[nb + r]; }
            float re[4] = {0.f, 0.f, 0.f, 0.f}, rt[4] = {0.f, 0.f, 0.f, 0.f};
            #pragma unroll
            for (int j = 0; j < 4; ++j) {
                floatx4 a = acc[ii][j];
                #pragma unroll
                for (int r = 0; r < 4; ++r) {
                    float zc = fmaf(-curv, a[r], cta[r] * tb[j]);
                    zc = fmaxf(zc, 1.0f + 1e-8f);
                    float lz = __log2f(zc);
                    float e = __builtin_amdgcn_exp2f(fmaf(c2, lz, sh2p));
                    float tl2 = (la[r] == lb[j]) ? fmaf(c1, lz, c1) : 0.0f;
                    re[r] += e; rt[r] += tl2;
                    colE[j] += e; colT[j] += tl2;
                }
            }
            #pragma unroll
            for (int r = 0; r < 4; ++r) {
                #pragma unroll
                for (int m = 1; m <= 8; m <<= 1) {
                    re[r] += __shfl_xor(re[r], m);
                    rt[r] += __shfl_xor(rt[r], m);
                }
            }
            #pragma unroll
            for (int r = 0; r < 4; ++r) {
                if (s == r) {
                    atomicAdd(&rsE[nb + r], re[r]);
                    atomicAdd(&rsT[nb + r], rt[r]);
                }
            }
        }
        #pragma unroll
        for (int j = 0; j < 4; ++j) {
            colE[j] += __shfl_xor(colE[j], 16); colE[j] += __shfl_xor(colE[j], 32);
            colT[j] += __shfl_xor(colT[j], 16); colT[j] += __shfl_xor(colT[j], 32);
            if (q == 0) {
                atomicAdd(&csE[mcol[j]], colE[j]);
                atomicAdd(&csT[mcol[j]], colT[j]);
            }
        }
        // next tile's step 0: lgkmcnt(0) + vmcnt(2) + barrier resync.
    }
#undef KSTEP
#undef TILE_PTRS
}

// ---- parallel finalize: 16 blocks, device-scope atomic accumulation; last
//      block (done counter) writes out. atomicAdd(p,0) read avoids stale L2. ----
__global__ __launch_bounds__(256) void finalize_kernel(
    const float* __restrict__ rsum_e, const float* __restrict__ rsum_t,
    const float* __restrict__ csum_e, const float* __restrict__ csum_t,
    const int* __restrict__ labels, const int* __restrict__ hist,
    const float* __restrict__ ent_partial,
    float* __restrict__ ce_acc, float* __restrict__ ent_acc,
    int* __restrict__ done, float* __restrict__ out) {
    __shared__ float red[4], red2[4];
    int b = blockIdx.x, tid = threadIdx.x;
    int n = b * 256 + tid;                 // covers 0..4095 exactly
    float Sn = (float)hist[labels[n]];
    float part = 0.0f;
    #pragma unroll
    for (int p = 0; p < 3; ++p) {
        part += Sn * (__logf(rsum_e[p * B_SZ + n]) - SHIFT) - rsum_t[p * B_SZ + n];
        part += Sn * (__logf(csum_e[p * B_SZ + n]) - SHIFT) - csum_t[p * B_SZ + n];
    }
    float ep = (b < 4) ? ent_partial[b * 256 + tid] : 0.0f;
    #pragma unroll
    for (int m = 1; m < 64; m <<= 1) {
        part += __shfl_xor(part, m);
        ep   += __shfl_xor(ep, m);
    }
    if ((tid & 63) == 0) { red[tid >> 6] = part; red2[tid >> 6] = ep; }
    __syncthreads();
    if (tid == 0) {
        atomicAdd(ce_acc, red[0] + red[1] + red[2] + red[3]);
        atomicAdd(ent_acc, red2[0] + red2[1] + red2[2] + red2[3]);
        __threadfence();
        if (atomicAdd(done, 1) == 15) {        // last of 16 blocks
            float ce = atomicAdd(ce_acc, 0.0f);    // coherent read
            float ent = atomicAdd(ent_acc, 0.0f);
            float contr = ce / (6.0f * (float)B_SZ);
            ent /= (float)B_SZ;
            out[0] = contr + 0.2f * ent;
            out[1] = contr;
            out[2] = ent;
        }
    }
}

// ---- workspace layout (bytes) ----
//   0       : fp8 feats (K-interleaved), 3*4096*512 = 6,291,456
//   6291456 : times[3][4096] f32   (49,152)
//   6340608 : rsum_e[12288 f]  \
//   6389760 : rsum_t           | zero region: 49155 floats
//   6438912 : csum_e           | (incl. ce_acc, ent_acc, done)
//   6488064 : csum_t           |
//   6537216 : ce_acc f32; 6537220: ent_acc f32; 6537224: done i32
//   6537228 : ent_partial[1024] f32 (every slot written by its dna block)
//   6541324 : hist[512] int (fully written by prep block 0)
extern "C" void kernel_launch(void* const* d_in, const int* in_sizes, int n_in,
                              void* d_out, int out_size, void* d_ws, size_t ws_size,
                              hipStream_t stream) {
    const float* img    = (const float*)d_in[0];
    const float* dna    = (const float*)d_in[1];
    const float* txt    = (const float*)d_in[2];
    const int*   labels = (const int*)d_in[3];
    const float* ls     = (const float*)d_in[4];
    const float* curv   = (const float*)d_in[5];

    char* ws = (char*)d_ws;
    u8*    f8     = (u8*)ws;
    float* times  = (float*)(ws + 6291456);
    float* rsum_e = (float*)(ws + 6340608);
    float* rsum_t = (float*)(ws + 6389760);
    float* csum_e = (float*)(ws + 6438912);
    float* csum_t = (float*)(ws + 6488064);
    float* ce_acc = (float*)(ws + 6537216);
    float* ent_acc= (float*)(ws + 6537220);
    int*   done   = (int*)  (ws + 6537224);
    float* ent_p  = (float*)(ws + 6537228);
    int*   hist   = (int*)  (ws + 6541324);

    prep_kernel<<<3072, 256, 0, stream>>>(img, dna, txt, curv, labels, hist,
                                          f8, times, rsum_e, ent_p);
    gemm_epi_kernel<<<512, 512, 0, stream>>>(f8, times, labels, ls, curv,
                                             rsum_e, rsum_t, csum_e, csum_t);
    finalize_kernel<<<16, 256, 0, stream>>>(rsum_e, rsum_t, csum_e, csum_t,
                                            labels, hist, ent_p,
                                            ce_acc, ent_acc, done, (float*)d_out);
}